// Round 1
// baseline (207.353 us; speedup 1.0000x reference)
//
#include <hip/hip_runtime.h>
#include <stdint.h>

#define B_N   8
#define C_N   256
#define H_N   96
#define W_N   128
#define KC    32
#define NCK   8          // C_N / KC
#define ND    21
#define NK    (ND * ND)  // 441

typedef __attribute__((ext_vector_type(8))) short short8;
typedef __attribute__((ext_vector_type(4))) float f32x4;

__device__ __forceinline__ uint32_t f2bf(float f) {
  uint32_t u = __builtin_bit_cast(uint32_t, f);
  return (u + 0x7fffu + ((u >> 16) & 1u)) >> 16;   // RNE
}
__device__ __forceinline__ uint32_t packbf(float lo, float hi) {
  return f2bf(lo) | (f2bf(hi) << 16);
}
__device__ __forceinline__ void async16(void* lds_dst, const void* gsrc) {
  __builtin_amdgcn_global_load_lds(
      (const __attribute__((address_space(1))) void*)gsrc,
      (__attribute__((address_space(3))) void*)lds_dst, 16, 0, 0);
}

// ---------------- prepass A: in1 fp32 NCHW -> bf16 [b][i][ck][je64][p2][cm32] ----------------
__global__ __launch_bounds__(256) void prep_a(const float* __restrict__ in1,
                                              unsigned short* __restrict__ Apre) {
  __shared__ float tile[KC][W_N + 1];
  int blk = blockIdx.x;                 // bi*8 + ck
  int ck = blk & 7, bi = blk >> 3;
  int b = bi / H_N, i = bi % H_N;
  const float* src = in1 + ((size_t)(b * C_N + ck * KC) * H_N + i) * W_N;
  int tid = threadIdx.x;
  for (int idx = tid; idx < KC * W_N; idx += 256) {
    int c = idx >> 7, j = idx & 127;
    tile[c][j] = src[(size_t)c * (H_N * W_N) + j];
  }
  __syncthreads();
  uint32_t* dst = (uint32_t*)(Apre + ((size_t)blk << 12));   // 4096 elems / chunk
  for (int q = tid; q < 2048; q += 256) {
    int cm2 = q & 15, p = (q >> 4) & 1, je = q >> 5;
    int j = 2 * je + p;
    dst[q] = packbf(tile[2 * cm2][j], tile[2 * cm2 + 1][j]);
  }
}

// ---------------- prepass B: in2 fp32 -> bf16 [b][y][ck][u96][p2][cm32], x-halo zeroed ------
__global__ __launch_bounds__(256) void prep_b(const float* __restrict__ in2,
                                              unsigned short* __restrict__ Bpre) {
  __shared__ float tile[KC][W_N + 1];
  int blk = blockIdx.x;
  int ck = blk & 7, bi = blk >> 3;
  int b = bi / H_N, y = bi % H_N;
  const float* src = in2 + ((size_t)(b * C_N + ck * KC) * H_N + y) * W_N;
  int tid = threadIdx.x;
  for (int idx = tid; idx < KC * W_N; idx += 256) {
    int c = idx >> 7, j = idx & 127;
    tile[c][j] = src[(size_t)c * (H_N * W_N) + j];
  }
  __syncthreads();
  uint32_t* dst = (uint32_t*)(Bpre + (size_t)blk * 6144);    // 6144 elems / chunk
  for (int q = tid; q < 3072; q += 256) {
    int cm2 = q & 15, p = (q >> 4) & 1, u = q >> 5;
    int x = 2 * u - 20 + p;        // u=je+dxi convention: x = 2*(u-10)+p
    uint32_t v = 0;
    if ((unsigned)x < 128u) v = packbf(tile[2 * cm2][x], tile[2 * cm2 + 1][x]);
    dst[q] = v;
  }
}

// ---------------- main: block = (b, i, dy-group of 3); banded X^T Y via 16x16x32 bf16 -------
__global__ __launch_bounds__(256, 4) void corr_main(const unsigned short* __restrict__ Apre,
                                                    const unsigned short* __restrict__ Bpre,
                                                    float* __restrict__ out) {
  __shared__ __align__(16) char lds[45056];
  char* Xl = lds;                    //  8192 B : X [je64][128B row: p*64 + cm*2], swizzled
  char* Yl = lds + 8192;             // 36864 B : Y [g3][u96][128B row], swizzled
  float* outl = (float*)(lds + 8192);  // epilogue reuse: [21][129] f32

  int h = blockIdx.x;
  int l = (h & 7) * 672 + (h >> 3);  // XCD-chunked remap (5376 = 8*672)
  int bi = l / 7, gidx = l - 7 * bi;
  int b = bi / H_N, i = bi % H_N;
  int dyb = gidx * 3;

  int tid = threadIdx.x;
  int lane = tid & 63, w = tid >> 6;   // 4 waves
  int p = w & 1, th = w >> 1;          // wave = (parity, t-half); t in {2*th, 2*th+1}
  int m = lane & 15, kg = lane >> 4;

  f32x4 acc[2][3][3];                  // [tt][g][delta]
#pragma unroll
  for (int a0 = 0; a0 < 2; ++a0)
#pragma unroll
    for (int a1 = 0; a1 < 3; ++a1)
#pragma unroll
      for (int a2 = 0; a2 < 3; ++a2) acc[a0][a1][a2] = {0.f, 0.f, 0.f, 0.f};

  // swizzled inner byte offset for A/B fragment reads (row&7 == m&7 for all our rows)
  uint32_t innsw = (uint32_t)(p * 64 + kg * 16) ^ ((uint32_t)(m & 7) << 4);

  for (int ck = 0; ck < NCK; ++ck) {
    __syncthreads();
    // ---- stage X (8192 B): 2 x 16B per thread, source pre-swizzled (rule #21)
    const char* Ab = (const char*)Apre + ((size_t)(bi * NCK + ck) << 13);
#pragma unroll
    for (int r = 0; r < 2; ++r) {
      uint32_t wb = (uint32_t)r * 4096u + (uint32_t)w * 1024u;
      uint32_t s = wb + (uint32_t)lane * 16u;
      uint32_t gb = s ^ (((s >> 7) & 7u) << 4);
      async16(Xl + wb, Ab + gb);
    }
    // ---- stage Y (3 rows x 12288 B), zero-fill out-of-range rows
#pragma unroll
    for (int q = 0; q < 9; ++q) {
      int L = w + q * 4;                       // 0..35, wave-uniform
      int g = L / 12, r12 = L - g * 12;
      int y = i + 2 * (dyb + g) - 20;
      char* lptr = Yl + L * 1024;
      if ((unsigned)y < (unsigned)H_N) {
        uint32_t s = (uint32_t)r12 * 1024u + (uint32_t)lane * 16u;
        uint32_t gb = s ^ (((s >> 7) & 7u) << 4);
        const char* Bb = (const char*)Bpre + (size_t)((b * H_N + y) * NCK + ck) * 12288;
        async16(lptr, Bb + gb);
      } else {
        short8 z = {};
        *(short8*)(lptr + lane * 16) = z;
      }
    }
    __syncthreads();
    // ---- compute: 2 A frags + 12 unique B frags -> 18 MFMAs
    short8 a0 = *(const short8*)(Xl + (16 * (2 * th + 0) + m) * 128 + innsw);
    short8 a1 = *(const short8*)(Xl + (16 * (2 * th + 1) + m) * 128 + innsw);
#pragma unroll
    for (int ss = 0; ss < 4; ++ss) {
      int s = 2 * th + ss;
      int u = 16 * s + m;
#pragma unroll
      for (int g = 0; g < 3; ++g) {
        short8 bb = *(const short8*)(Yl + g * 12288 + u * 128 + innsw);
        if (ss <= 2) acc[0][g][ss]     = __builtin_amdgcn_mfma_f32_16x16x32_bf16(a0, bb, acc[0][g][ss], 0, 0, 0);
        if (ss >= 1) acc[1][g][ss - 1] = __builtin_amdgcn_mfma_f32_16x16x32_bf16(a1, bb, acc[1][g][ss - 1], 0, 0, 0);
      }
    }
  }

  // ---- epilogue: band-extract via LDS, coalesced stores
#pragma unroll
  for (int g = 0; g < 3; ++g) {
    __syncthreads();   // also protects Yl reuse on first iter
#pragma unroll
    for (int tt = 0; tt < 2; ++tt) {
      int t = 2 * th + tt;
#pragma unroll
      for (int dl = 0; dl < 3; ++dl) {
#pragma unroll
        for (int r = 0; r < 4; ++r) {
          int a_ = kg * 4 + r;               // row within tile (m)
          int dxi = 16 * dl + m - a_;        // col(n)=m (lane&15)
          if (dxi >= 0 && dxi <= 20) {
            int j = 2 * (16 * t + a_) + p;
            outl[dxi * 129 + j] = acc[tt][g][dl][r];
          }
        }
      }
    }
    __syncthreads();
    int dyi = dyb + g;
    size_t obase = ((size_t)(b * NK + dyi * ND) * H_N + i) * W_N;
    for (int idx = tid; idx < ND * W_N; idx += 256) {
      int dxi = idx >> 7, j = idx & 127;
      out[obase + (size_t)dxi * (H_N * W_N) + j] = outl[dxi * 129 + j];
    }
  }
}

// ---------------- fallback (only if workspace too small) ----------------
__global__ void corr_naive(const float* __restrict__ in1, const float* __restrict__ in2,
                           float* __restrict__ out) {
  size_t o = (size_t)blockIdx.x * 256 + threadIdx.x;
  const size_t total = (size_t)B_N * NK * H_N * W_N;
  if (o >= total) return;
  int j = o & 127;
  int i = (int)((o >> 7) % H_N);
  int k = (int)((o / ((size_t)H_N * W_N)) % NK);
  int b = (int)(o / ((size_t)NK * H_N * W_N));
  int dyi = k / ND, dxi = k % ND;
  int y = i + 2 * dyi - 20, x = j + 2 * dxi - 20;
  float s = 0.f;
  if ((unsigned)y < (unsigned)H_N && (unsigned)x < (unsigned)W_N) {
    const float* p1 = in1 + ((size_t)b * C_N * H_N + i) * W_N + j;
    const float* p2 = in2 + ((size_t)b * C_N * H_N + y) * W_N + x;
    for (int c = 0; c < C_N; ++c)
      s += p1[(size_t)c * H_N * W_N] * p2[(size_t)c * H_N * W_N];
  }
  out[o] = s;
}

extern "C" void kernel_launch(void* const* d_in, const int* in_sizes, int n_in,
                              void* d_out, int out_size, void* d_ws, size_t ws_size,
                              hipStream_t stream) {
  const float* in1 = (const float*)d_in[0];
  const float* in2 = (const float*)d_in[1];
  float* out = (float*)d_out;

  const size_t A_BYTES = (size_t)B_N * H_N * NCK * 64 * 64 * 2;   // 50,331,648
  const size_t B_BYTES = (size_t)B_N * H_N * NCK * 96 * 64 * 2;   // 75,497,472
  if (ws_size < A_BYTES + B_BYTES) {
    size_t total = (size_t)B_N * NK * H_N * W_N;
    corr_naive<<<(int)((total + 255) / 256), 256, 0, stream>>>(in1, in2, out);
    return;
  }
  unsigned short* Apre = (unsigned short*)d_ws;
  unsigned short* Bpre = (unsigned short*)((char*)d_ws + A_BYTES);

  prep_a<<<B_N * H_N * NCK, 256, 0, stream>>>(in1, Apre);
  prep_b<<<B_N * H_N * NCK, 256, 0, stream>>>(in2, Bpre);
  corr_main<<<5376, 256, 0, stream>>>(Apre, Bpre, out);
}